// Round 9
// baseline (37.740 us; speedup 1.0000x reference)
//
#include <hip/hip_runtime.h>
#include <hip/hip_fp16.h>

#define BATCH  1024
#define NVARS  2048
#define N_OUT  4096

#define W8BYTES (NVARS * 16)     // 32 KB per 8-col window
#define NW8     (BATCH / 8)      // 128 windows

typedef float f32x4 __attribute__((ext_vector_type(4)));

__device__ __forceinline__ __half2 u2h2(unsigned u) {
    union { unsigned u; __half2 h; } c; c.u = u; return c.h;
}
__device__ __forceinline__ unsigned h22u(__half2 h) {
    union { unsigned u; __half2 h; } c; c.h = h; return c.u;
}
__device__ __forceinline__ void sel2sc(unsigned sel, unsigned& s, unsigned& c) {
    // half2 constants: 1.0h2 = 0x3C003C00, -1.0h2 = 0xBC00BC00
    c = (sel & 1u) ? 0x3C003C00u : 0u;
    s = (sel == 2u) ? 0x3C003C00u : (sel == 3u) ? 0xBC00BC00u : 0u;
}

// ---------------- prep: LDS-tile transpose to window-major fp16 + T-flatten ----
// xh2: [128 w08][2048 row][8 cols] fp16; byte(w08,r) = w08*32768 + r*16
// T[i*8+m] = leafA | leafB<<16, leaf = sel<<11 | row. sel:0->0,1->1,2->x,3->1-x
__global__ __launch_bounds__(256) void prep_kernel(
    const float* __restrict__ x,
    const int2* __restrict__ idx0,
    const int2* __restrict__ idx1,
    const int2* __restrict__ idx2,
    const int2* __restrict__ idx3,
    unsigned* __restrict__ T,
    char* __restrict__ xh2)
{
    __shared__ char tile[64 * 272];    // 64 rows x 128 cols fp16, 272B padded rows

    const int bid = blockIdx.x;        // 256 blocks
    const int tid = threadIdx.x;
    const int rt  = bid >> 3;          // row tile 0..31
    const int ct  = bid & 7;           // col tile 0..7 (128 cols each)
    const int r0  = rt * 64;

    // ---- T-flatten on blocks 0..15 ----
    if (bid < 16) {
        const int i = bid * 256 + tid;
        int2 p3 = idx3[i];
        int n = 0;
        #pragma unroll
        for (int t = 0; t < 2; ++t) {
            int2 p2 = idx2[t ? p3.y : p3.x];
            #pragma unroll
            for (int u = 0; u < 2; ++u) {
                int2 p1 = idx1[u ? p2.y : p2.x];
                #pragma unroll
                for (int v = 0; v < 2; ++v) {
                    int2 p0 = idx0[v ? p1.y : p1.x];
                    unsigned w = 0;
                    #pragma unroll
                    for (int e = 0; e < 2; ++e) {
                        int k = e ? p0.y : p0.x;
                        unsigned code;
                        if (k < 2) code = (unsigned)k << 11;
                        else       code = ((2u + (k & 1)) << 11) | ((unsigned)(k - 2) >> 1);
                        w |= code << (16 * e);
                    }
                    T[(size_t)i * 8 + n] = w;
                    ++n;
                }
            }
        }
    }

    // ---- phase A: coalesced read of 64 rows x 128 cols, cvt fp16 into tile ----
    {
        const int r_l = tid >> 5;      // 0..7
        const int c4  = tid & 31;      // 0..31 float4 units
        #pragma unroll
        for (int q = 0; q < 8; ++q) {
            const int rr = q * 8 + r_l;                 // tile row 0..63
            float4 v = ((const float4*)x)[(size_t)(r0 + rr) * 256 + ct * 32 + c4];
            unsigned h0 = h22u(__floats2half2_rn(v.x, v.y));
            unsigned h1 = h22u(__floats2half2_rn(v.z, v.w));
            unsigned* p = (unsigned*)(tile + rr * 272 + c4 * 8);
            p[0] = h0; p[1] = h1;
        }
    }
    __syncthreads();

    // ---- phase B: write window-major, 1 KB contiguous per wave ----
    {
        const int r2 = tid & 63;
        const int wl = tid >> 6;       // 0..3
        #pragma unroll
        for (int pp = 0; pp < 4; ++pp) {
            const int w08l = pp * 4 + wl;              // 0..15
            uint4 v = *(const uint4*)(tile + r2 * 272 + w08l * 16);
            const int w08 = ct * 16 + w08l;
            *(uint4*)(xh2 + (size_t)w08 * W8BYTES + (r0 + r2) * 16) = v;
        }
    }
}

// ---------------- main: one 32 KB window per block, L1-resident gathers --------
// 256 blocks x 512 threads, 1 block/CU (forced by LDS spacer). block =
// (window w = bx>>1, output half = (bx&1)*2048). 4 passes x 512 outputs.
// No barriers, no staging: pass-0 gathers fault the window into L1; passes
// 1..3 are L1 hits. T-loads for pass p+1 issued before pass p's tree math.
__global__ __launch_bounds__(512) void knowledge_main(
    const char* __restrict__ xh2,
    const uint4* __restrict__ T4,     // 2 x uint4 per output (8 packed pair-words)
    float* __restrict__ out)
{
    __shared__ char spacer[90112];    // forces 1 block/CU (2x90112 > 160 KiB)
    if ((int)blockIdx.x == -1) ((volatile char*)spacer)[0] = 1;

    const int bx  = blockIdx.x;       // 256
    const int tid = threadIdx.x;      // 0..511
    const int w   = bx >> 1;          // window 0..127 (cols w*8 .. w*8+7)
    const char* base = xh2 + (size_t)w * W8BYTES;

    int o = (bx & 1) * 2048 + tid;    // output row for pass 0
    uint4 t0 = T4[(size_t)o * 2];
    uint4 t1 = T4[(size_t)o * 2 + 1];

    #pragma unroll
    for (int pass = 0; pass < 4; ++pass) {
        const unsigned tw[8] = {t0.x, t0.y, t0.z, t0.w, t1.x, t1.y, t1.z, t1.w};

        // 16 x 16 B gathers from the L1-resident window
        uint4 Av[8], Bv[8];
        #pragma unroll
        for (int m = 0; m < 8; ++m) {
            Av[m] = *(const uint4*)(base + ((tw[m] & 0x7FFu) << 4));
            Bv[m] = *(const uint4*)(base + (((tw[m] >> 16) & 0x7FFu) << 4));
        }

        // prefetch next pass's T while gathers are in flight
        if (pass < 3) {
            const int on = o + 512;
            t0 = T4[(size_t)on * 2];
            t1 = T4[(size_t)on * 2 + 1];
        }

        float accp[8];
        #pragma unroll
        for (int k2 = 0; k2 < 8; ++k2) accp[k2] = 0.f;

        #pragma unroll
        for (int a3 = 0; a3 < 2; ++a3) {                 // top SumLayer
            __half2 prod2[4];
            #pragma unroll
            for (int a2 = 0; a2 < 2; ++a2) {             // ProductLayer
                __half2 sum1[4];
                #pragma unroll
                for (int a1 = 0; a1 < 2; ++a1) {         // SumLayer
                    const int m = a3 * 4 + a2 * 2 + a1;
                    unsigned sa, ca, sb, cb;
                    sel2sc((tw[m] >> 11) & 3u, sa, ca);
                    sel2sc((tw[m] >> 27) & 3u, sb, cb);
                    const unsigned aw[4] = {Av[m].x, Av[m].y, Av[m].z, Av[m].w};
                    const unsigned bw[4] = {Bv[m].x, Bv[m].y, Bv[m].z, Bv[m].w};
                    #pragma unroll
                    for (int k = 0; k < 4; ++k) {
                        __half2 va = __hfma2(u2h2(aw[k]), u2h2(sa), u2h2(ca));
                        __half2 vb = __hfma2(u2h2(bw[k]), u2h2(sb), u2h2(cb));
                        __half2 pr = __hmul2(va, vb);    // leaf product
                        sum1[k] = (a1 == 0) ? pr : __hadd2(sum1[k], pr);
                    }
                }
                #pragma unroll
                for (int k = 0; k < 4; ++k)
                    prod2[k] = (a2 == 0) ? sum1[k] : __hmul2(prod2[k], sum1[k]);
            }
            #pragma unroll
            for (int k = 0; k < 4; ++k) {
                float2 pf = __half22float2(prod2[k]);
                accp[k * 2]     += pf.x;
                accp[k * 2 + 1] += pf.y;
            }
        }

        // NT store: this output row's 8 cols (32 B), bypass caches
        float* dst = out + (size_t)o * BATCH + w * 8;
        f32x4 o0 = {accp[0], accp[1], accp[2], accp[3]};
        f32x4 o1 = {accp[4], accp[5], accp[6], accp[7]};
        __builtin_nontemporal_store(o0, reinterpret_cast<f32x4*>(dst));
        __builtin_nontemporal_store(o1, reinterpret_cast<f32x4*>(dst) + 1);

        o += 512;
    }
}

// ---------------- fallback (round-1 kernel) if ws too small ----------------
__device__ __forceinline__ float Hval(int k, const float* __restrict__ x, int b) {
    if (k < 2) return (float)k;
    float v = x[((k - 2) >> 1) * BATCH + b];
    return (k & 1) ? 1.0f - v : v;
}

__global__ __launch_bounds__(256) void knowledge_fused_kernel(
    const float* __restrict__ x,
    const int2* __restrict__ idx0,
    const int2* __restrict__ idx1,
    const int2* __restrict__ idx2,
    const int2* __restrict__ idx3,
    float* __restrict__ out)
{
    const int i = blockIdx.x;
    const int b = blockIdx.y * blockDim.x + threadIdx.x;
    const int2 p3 = idx3[i];
    float acc3 = 0.0f;
    #pragma unroll
    for (int t = 0; t < 2; ++t) {
        const int2 p2 = idx2[t ? p3.y : p3.x];
        float prod2 = 1.0f;
        #pragma unroll
        for (int u = 0; u < 2; ++u) {
            const int2 p1 = idx1[u ? p2.y : p2.x];
            float sum1 = 0.0f;
            #pragma unroll
            for (int v = 0; v < 2; ++v) {
                const int2 p0 = idx0[v ? p1.y : p1.x];
                sum1 += Hval(p0.x, x, b) * Hval(p0.y, x, b);
            }
            prod2 *= sum1;
        }
        acc3 += prod2;
    }
    out[(size_t)i * BATCH + b] = acc3;
}

extern "C" void kernel_launch(void* const* d_in, const int* in_sizes, int n_in,
                              void* d_out, int out_size, void* d_ws, size_t ws_size,
                              hipStream_t stream) {
    const float* x    = (const float*)d_in[0];
    const int2*  idx0 = (const int2*)d_in[1];
    const int2*  idx1 = (const int2*)d_in[2];
    const int2*  idx2 = (const int2*)d_in[3];
    const int2*  idx3 = (const int2*)d_in[4];
    float* out = (float*)d_out;

    const size_t t_bytes   = (size_t)N_OUT * 8 * sizeof(unsigned);   // 128 KB
    const size_t xh2_bytes = (size_t)NW8 * W8BYTES;                  // 4 MB
    if (ws_size >= t_bytes + xh2_bytes) {
        unsigned* T   = (unsigned*)d_ws;
        char*     xh2 = (char*)d_ws + t_bytes;
        prep_kernel<<<256, 256, 0, stream>>>(x, idx0, idx1, idx2, idx3, T, xh2);
        knowledge_main<<<256, 512, 0, stream>>>(xh2, (const uint4*)T, out);
    } else {
        dim3 grid(N_OUT, BATCH / 256);
        knowledge_fused_kernel<<<grid, 256, 0, stream>>>(x, idx0, idx1, idx2, idx3, out);
    }
}

// Round 10
// 28.753 us; speedup vs baseline: 1.3126x; 1.3126x over previous
//
#include <hip/hip_runtime.h>
#include <hip/hip_fp16.h>

#define BATCH  1024
#define NVARS  2048
#define N_OUT  4096

#define W32BYTES (NVARS * 64)    // 128 KB per 32-col window (fp16)
#define NW32     (BATCH / 32)    // 32 windows

typedef float f32x4 __attribute__((ext_vector_type(4)));

__device__ __forceinline__ __half2 u2h2(unsigned u) {
    union { unsigned u; __half2 h; } c; c.u = u; return c.h;
}
__device__ __forceinline__ unsigned h22u(__half2 h) {
    union { unsigned u; __half2 h; } c; c.h = h; return c.u;
}
__device__ __forceinline__ void sel2sc(unsigned sel, unsigned& s, unsigned& c) {
    // half2 constants: 1.0h2 = 0x3C003C00, -1.0h2 = 0xBC00BC00
    c = (sel & 1u) ? 0x3C003C00u : 0u;
    s = (sel == 2u) ? 0x3C003C00u : (sel == 3u) ? 0xBC00BC00u : 0u;
}

// ---------------- prep: LDS-tile transpose to 32-col-window fp16 + T-flatten ----
// xh2: [32 w][2048 r][32 cols fp16 = 64 B]; byte(w,r) = w*131072 + r*64
// T[i*8+m] = leafA | leafB<<16, leaf = sel<<11 | row. sel:0->0,1->1,2->x,3->1-x
__global__ __launch_bounds__(256) void prep_kernel(
    const float* __restrict__ x,
    const int2* __restrict__ idx0,
    const int2* __restrict__ idx1,
    const int2* __restrict__ idx2,
    const int2* __restrict__ idx3,
    unsigned* __restrict__ T,
    char* __restrict__ xh2)
{
    __shared__ char tile[64 * 272];    // 64 rows x 128 cols fp16, 272B padded rows

    const int bid = blockIdx.x;        // 256 blocks
    const int tid = threadIdx.x;
    const int rt  = bid >> 3;          // row tile 0..31
    const int ct  = bid & 7;           // col tile 0..7 (128 cols each)
    const int r0  = rt * 64;

    // ---- T-flatten on blocks 0..15 ----
    if (bid < 16) {
        const int i = bid * 256 + tid;
        int2 p3 = idx3[i];
        int n = 0;
        #pragma unroll
        for (int t = 0; t < 2; ++t) {
            int2 p2 = idx2[t ? p3.y : p3.x];
            #pragma unroll
            for (int u = 0; u < 2; ++u) {
                int2 p1 = idx1[u ? p2.y : p2.x];
                #pragma unroll
                for (int v = 0; v < 2; ++v) {
                    int2 p0 = idx0[v ? p1.y : p1.x];
                    unsigned w = 0;
                    #pragma unroll
                    for (int e = 0; e < 2; ++e) {
                        int k = e ? p0.y : p0.x;
                        unsigned code;
                        if (k < 2) code = (unsigned)k << 11;
                        else       code = ((2u + (k & 1)) << 11) | ((unsigned)(k - 2) >> 1);
                        w |= code << (16 * e);
                    }
                    T[(size_t)i * 8 + n] = w;
                    ++n;
                }
            }
        }
    }

    // ---- phase A: coalesced read of 64 rows x 128 cols, cvt fp16 into tile ----
    {
        const int r_l = tid >> 5;      // 0..7
        const int c4  = tid & 31;      // 0..31 float4 units
        #pragma unroll
        for (int q = 0; q < 8; ++q) {
            const int rr = q * 8 + r_l;                 // tile row 0..63
            float4 v = ((const float4*)x)[(size_t)(r0 + rr) * 256 + ct * 32 + c4];
            unsigned h0 = h22u(__floats2half2_rn(v.x, v.y));
            unsigned h1 = h22u(__floats2half2_rn(v.z, v.w));
            unsigned* p = (unsigned*)(tile + rr * 272 + c4 * 8);
            p[0] = h0; p[1] = h1;
        }
    }
    __syncthreads();

    // ---- phase B: write w32-major; per inst 64 lanes = 1 KB contiguous ----
    {
        const int wl = tid & 3;        // 16-B piece within 64-B row-piece
        const int r2 = tid >> 2;       // 0..63
        #pragma unroll
        for (int g = 0; g < 4; ++g) {  // 32-col group within the 128-col tile
            uint4 v = *(const uint4*)(tile + r2 * 272 + g * 64 + wl * 16);
            const int w32 = ct * 4 + g;
            *(uint4*)(xh2 + (size_t)w32 * W32BYTES + (r0 + r2) * 64 + wl * 16) = v;
        }
    }
}

// ---------------- main: 128 KB LDS window, quartered layout, full-line stores ----
// 256 blocks x 1024 threads (1 block/CU, 16 waves). block = (w = bx>>3, chunk =
// bx&7 -> 512 outputs). LDS quarter q holds cols 8q..8q+7: addr = q*32768 + r*16
// -> ds_read_b128 banks spread by 4*(r%8). Stores via LDS transpose: full 128-B
// out lines (8 lanes x 16 B).
__global__ __launch_bounds__(1024) void knowledge_main(
    const char* __restrict__ xh2,
    const uint4* __restrict__ T4,     // 2 x uint4 per output (8 packed pair-words)
    float* __restrict__ out)
{
    __shared__ char lds[131072];      // 128 KiB: stage area, then store-transpose

    const int bx    = blockIdx.x;     // 256
    const int tid   = threadIdx.x;    // 0..1023
    const int w     = bx >> 3;        // window 0..31 (cols w*32..w*32+31)
    const int chunk = bx & 7;         // output chunk (512 outputs)

    // ---- stage: 128 KB coalesced read, quartered LDS write ----
    {
        const char* src = xh2 + (size_t)w * W32BYTES;
        #pragma unroll
        for (int it = 0; it < 8; ++it) {
            const int idx = it * 1024 + tid;       // 16-B piece 0..8191
            uint4 v = *(const uint4*)(src + idx * 16);
            const int r = idx >> 2, q = idx & 3;
            *(uint4*)(lds + q * 32768 + r * 16) = v;
        }
    }
    __syncthreads();

    const int ol = tid >> 1;          // output-in-chunk 0..511
    const int h  = tid & 1;           // 16-col half (quarters 2h, 2h+1)
    const int o  = chunk * 512 + ol;
    const char* baseq = lds + h * 65536;

    uint4 t0 = T4[(size_t)o * 2];
    uint4 t1 = T4[(size_t)o * 2 + 1];
    const unsigned tw[8] = {t0.x, t0.y, t0.z, t0.w, t1.x, t1.y, t1.z, t1.w};

    float accf[16];
    #pragma unroll
    for (int k = 0; k < 16; ++k) accf[k] = 0.f;

    #pragma unroll
    for (int a3 = 0; a3 < 2; ++a3) {                 // top SumLayer
        unsigned prod2[8];
        #pragma unroll
        for (int a2 = 0; a2 < 2; ++a2) {             // ProductLayer
            unsigned sum1[8];
            #pragma unroll
            for (int a1 = 0; a1 < 2; ++a1) {         // SumLayer
                const int m = a3 * 4 + a2 * 2 + a1;
                const unsigned wv = tw[m];
                const int offA = (int)((wv & 0x7FFu) << 4);
                const int offB = (int)(((wv >> 16) & 0x7FFu) << 4);
                uint4 A0 = *(const uint4*)(baseq + offA);
                uint4 A1 = *(const uint4*)(baseq + 32768 + offA);
                uint4 B0 = *(const uint4*)(baseq + offB);
                uint4 B1 = *(const uint4*)(baseq + 32768 + offB);
                unsigned sa, ca, sb, cb;
                sel2sc((wv >> 11) & 3u, sa, ca);
                sel2sc((wv >> 27) & 3u, sb, cb);
                const unsigned aw[8] = {A0.x,A0.y,A0.z,A0.w,A1.x,A1.y,A1.z,A1.w};
                const unsigned bw[8] = {B0.x,B0.y,B0.z,B0.w,B1.x,B1.y,B1.z,B1.w};
                #pragma unroll
                for (int k = 0; k < 8; ++k) {
                    __half2 va = __hfma2(u2h2(aw[k]), u2h2(sa), u2h2(ca));
                    __half2 vb = __hfma2(u2h2(bw[k]), u2h2(sb), u2h2(cb));
                    __half2 pr = __hmul2(va, vb);    // leaf product
                    sum1[k] = (a1 == 0) ? h22u(pr)
                                        : h22u(__hadd2(u2h2(sum1[k]), pr));
                }
            }
            #pragma unroll
            for (int k = 0; k < 8; ++k)
                prod2[k] = (a2 == 0) ? sum1[k]
                                     : h22u(__hmul2(u2h2(prod2[k]), u2h2(sum1[k])));
        }
        #pragma unroll
        for (int k = 0; k < 8; ++k) {                // top sum in f32
            float2 pf = __half22float2(u2h2(prod2[k]));
            accf[2 * k]     += pf.x;
            accf[2 * k + 1] += pf.y;
        }
    }

    // ---- store transpose: acc -> LDS (stride 144), then full-line NT stores ----
    __syncthreads();                  // staging data dead from here
    #pragma unroll
    for (int k = 0; k < 4; ++k) {
        f32x4 v = {accf[4*k], accf[4*k+1], accf[4*k+2], accf[4*k+3]};
        *reinterpret_cast<f32x4*>(lds + ol * 144 + h * 64 + k * 16) = v;
    }
    __syncthreads();
    #pragma unroll
    for (int it = 0; it < 4; ++it) {
        const int p  = it * 1024 + tid;              // f32x4 piece 0..4095
        const int o2 = p >> 3, pc = p & 7;
        f32x4 v = *reinterpret_cast<const f32x4*>(lds + o2 * 144 + pc * 16);
        float* dst = out + (size_t)(chunk * 512 + o2) * BATCH + w * 32 + pc * 4;
        __builtin_nontemporal_store(v, reinterpret_cast<f32x4*>(dst));
    }
}

// ---------------- fallback (round-1 kernel) if ws too small ----------------
__device__ __forceinline__ float Hval(int k, const float* __restrict__ x, int b) {
    if (k < 2) return (float)k;
    float v = x[((k - 2) >> 1) * BATCH + b];
    return (k & 1) ? 1.0f - v : v;
}

__global__ __launch_bounds__(256) void knowledge_fused_kernel(
    const float* __restrict__ x,
    const int2* __restrict__ idx0,
    const int2* __restrict__ idx1,
    const int2* __restrict__ idx2,
    const int2* __restrict__ idx3,
    float* __restrict__ out)
{
    const int i = blockIdx.x;
    const int b = blockIdx.y * blockDim.x + threadIdx.x;
    const int2 p3 = idx3[i];
    float acc3 = 0.0f;
    #pragma unroll
    for (int t = 0; t < 2; ++t) {
        const int2 p2 = idx2[t ? p3.y : p3.x];
        float prod2 = 1.0f;
        #pragma unroll
        for (int u = 0; u < 2; ++u) {
            const int2 p1 = idx1[u ? p2.y : p2.x];
            float sum1 = 0.0f;
            #pragma unroll
            for (int v = 0; v < 2; ++v) {
                const int2 p0 = idx0[v ? p1.y : p1.x];
                sum1 += Hval(p0.x, x, b) * Hval(p0.y, x, b);
            }
            prod2 *= sum1;
        }
        acc3 += prod2;
    }
    out[(size_t)i * BATCH + b] = acc3;
}

extern "C" void kernel_launch(void* const* d_in, const int* in_sizes, int n_in,
                              void* d_out, int out_size, void* d_ws, size_t ws_size,
                              hipStream_t stream) {
    const float* x    = (const float*)d_in[0];
    const int2*  idx0 = (const int2*)d_in[1];
    const int2*  idx1 = (const int2*)d_in[2];
    const int2*  idx2 = (const int2*)d_in[3];
    const int2*  idx3 = (const int2*)d_in[4];
    float* out = (float*)d_out;

    const size_t t_bytes   = (size_t)N_OUT * 8 * sizeof(unsigned);   // 128 KB
    const size_t xh2_bytes = (size_t)NW32 * W32BYTES;                // 4 MB
    if (ws_size >= t_bytes + xh2_bytes) {
        unsigned* T   = (unsigned*)d_ws;
        char*     xh2 = (char*)d_ws + t_bytes;
        prep_kernel<<<256, 256, 0, stream>>>(x, idx0, idx1, idx2, idx3, T, xh2);
        knowledge_main<<<256, 1024, 0, stream>>>(xh2, (const uint4*)T, out);
    } else {
        dim3 grid(N_OUT, BATCH / 256);
        knowledge_fused_kernel<<<grid, 256, 0, stream>>>(x, idx0, idx1, idx2, idx3, out);
    }
}

// Round 11
// 19.182 us; speedup vs baseline: 1.9675x; 1.4990x over previous
//
#include <hip/hip_runtime.h>
#include <hip/hip_fp16.h>

#define BATCH  1024
#define NVARS  2048
#define N_OUT  4096

#define W32BYTES (NVARS * 64)    // 128 KB per 32-col window (fp16, row = 64 B)
#define NW32     (BATCH / 32)    // 32 windows

typedef float f32x4 __attribute__((ext_vector_type(4)));

__device__ __forceinline__ __half2 u2h2(unsigned u) {
    union { unsigned u; __half2 h; } c; c.u = u; return c.h;
}
__device__ __forceinline__ unsigned h22u(__half2 h) {
    union { unsigned u; __half2 h; } c; c.h = h; return c.u;
}
__device__ __forceinline__ void sel2sc(unsigned sel, unsigned& s, unsigned& c) {
    // half2 constants: 1.0h2 = 0x3C003C00, -1.0h2 = 0xBC00BC00
    c = (sel & 1u) ? 0x3C003C00u : 0u;
    s = (sel == 2u) ? 0x3C003C00u : (sel == 3u) ? 0xBC00BC00u : 0u;
}

// ---------------- prep: LDS-tile transpose to 32-col-window fp16 + T-flatten ----
// xh2: [32 w][2048 r][32 cols fp16 = 64 B]; byte(w,r) = w*131072 + r*64
// T[i*8+m] = leafA | leafB<<16, leaf = sel<<11 | row. sel:0->0,1->1,2->x,3->1-x
__global__ __launch_bounds__(256) void prep_kernel(
    const float* __restrict__ x,
    const int2* __restrict__ idx0,
    const int2* __restrict__ idx1,
    const int2* __restrict__ idx2,
    const int2* __restrict__ idx3,
    unsigned* __restrict__ T,
    char* __restrict__ xh2)
{
    __shared__ char tile[64 * 272];    // 64 rows x 128 cols fp16, 272B padded rows

    const int bid = blockIdx.x;        // 256 blocks
    const int tid = threadIdx.x;
    const int rt  = bid >> 3;          // row tile 0..31
    const int ct  = bid & 7;           // col tile 0..7 (128 cols each)
    const int r0  = rt * 64;

    // ---- T-flatten on blocks 0..15 ----
    if (bid < 16) {
        const int i = bid * 256 + tid;
        int2 p3 = idx3[i];
        int n = 0;
        #pragma unroll
        for (int t = 0; t < 2; ++t) {
            int2 p2 = idx2[t ? p3.y : p3.x];
            #pragma unroll
            for (int u = 0; u < 2; ++u) {
                int2 p1 = idx1[u ? p2.y : p2.x];
                #pragma unroll
                for (int v = 0; v < 2; ++v) {
                    int2 p0 = idx0[v ? p1.y : p1.x];
                    unsigned w = 0;
                    #pragma unroll
                    for (int e = 0; e < 2; ++e) {
                        int k = e ? p0.y : p0.x;
                        unsigned code;
                        if (k < 2) code = (unsigned)k << 11;
                        else       code = ((2u + (k & 1)) << 11) | ((unsigned)(k - 2) >> 1);
                        w |= code << (16 * e);
                    }
                    T[(size_t)i * 8 + n] = w;
                    ++n;
                }
            }
        }
    }

    // ---- phase A: coalesced read of 64 rows x 128 cols, cvt fp16 into tile ----
    {
        const int r_l = tid >> 5;      // 0..7
        const int c4  = tid & 31;      // 0..31 float4 units
        #pragma unroll
        for (int q = 0; q < 8; ++q) {
            const int rr = q * 8 + r_l;                 // tile row 0..63
            float4 v = ((const float4*)x)[(size_t)(r0 + rr) * 256 + ct * 32 + c4];
            unsigned h0 = h22u(__floats2half2_rn(v.x, v.y));
            unsigned h1 = h22u(__floats2half2_rn(v.z, v.w));
            unsigned* p = (unsigned*)(tile + rr * 272 + c4 * 8);
            p[0] = h0; p[1] = h1;
        }
    }
    __syncthreads();

    // ---- phase B: write w32-major; per inst 64 lanes = 1 KB contiguous ----
    {
        const int wl = tid & 3;        // 16-B piece within 64-B row
        const int r2 = tid >> 2;       // 0..63
        #pragma unroll
        for (int g = 0; g < 4; ++g) {  // 32-col group within the 128-col tile
            uint4 v = *(const uint4*)(tile + r2 * 272 + g * 64 + wl * 16);
            const int w32 = ct * 4 + g;
            *(uint4*)(xh2 + (size_t)w32 * W32BYTES + (r0 + r2) * 64 + wl * 16) = v;
        }
    }
}

// ---------------- main: 128 KiB LDS window, row-major, XCD-affine ----------------
// 256 blocks x 512 threads, 1 block/CU (128 KiB LDS), 2 waves/SIMD (256-VGPR
// budget, no spills). XCD k (= bx&7) owns windows 4k..4k+3 -> stages only
// 512 KB, L2-resident. Thread = (output ol, col-group cg of 8 cols); a wave's
// ds_read_b128 spreads 16 rows x 4 cgs across banks (near-conflict-free).
// Lanes 4i..4i+3 store 128 B contiguous -> full-line NT stores.
__global__ __launch_bounds__(512) void knowledge_main(
    const char* __restrict__ xh2,
    const uint4* __restrict__ T4,     // 2 x uint4 per output (8 packed pair-words)
    float* __restrict__ out)
{
    __shared__ char lds[131072];      // the 32-col window: row r at byte r*64

    const int bx   = blockIdx.x;      // 256
    const int tid  = threadIdx.x;     // 0..511
    const int xcd  = bx & 7;
    const int slot = bx >> 3;         // 0..31
    const int w    = xcd * 4 + (slot & 3);   // window 0..31 (cols w*32..)
    const int chunk= slot >> 2;       // 0..7 (512 outputs each)

    // ---- stage: linear 128 KiB copy (1 KB contiguous per wave-instr) ----
    {
        const char* src = xh2 + (size_t)w * W32BYTES;
        #pragma unroll
        for (int it = 0; it < 16; ++it) {
            const int u = it * 512 + tid;          // 16-B unit 0..8191
            *(uint4*)(lds + u * 16) = *(const uint4*)(src + u * 16);
        }
    }
    __syncthreads();

    const int cg  = tid & 3;          // col group 0..3 (8 cols)
    const int ol  = tid >> 2;         // output-in-pass 0..127
    const int cgb = cg * 16;          // byte offset within 64-B row

    #pragma unroll 1
    for (int pass = 0; pass < 4; ++pass) {
        const int o = chunk * 512 + pass * 128 + ol;
        uint4 t0 = T4[(size_t)o * 2];
        uint4 t1 = T4[(size_t)o * 2 + 1];
        const unsigned tw[8] = {t0.x, t0.y, t0.z, t0.w, t1.x, t1.y, t1.z, t1.w};

        float accf[8];
        #pragma unroll
        for (int k = 0; k < 8; ++k) accf[k] = 0.f;

        #pragma unroll
        for (int a3 = 0; a3 < 2; ++a3) {                 // top SumLayer
            __half2 prod2[4];
            #pragma unroll
            for (int a2 = 0; a2 < 2; ++a2) {             // ProductLayer
                __half2 sum1[4];
                #pragma unroll
                for (int a1 = 0; a1 < 2; ++a1) {         // SumLayer
                    const int m = a3 * 4 + a2 * 2 + a1;
                    const unsigned wv = tw[m];
                    uint4 A = *(const uint4*)(lds + ((wv & 0x7FFu) << 6) + cgb);
                    uint4 B = *(const uint4*)(lds + (((wv >> 16) & 0x7FFu) << 6) + cgb);
                    unsigned sa, ca, sb, cb;
                    sel2sc((wv >> 11) & 3u, sa, ca);
                    sel2sc((wv >> 27) & 3u, sb, cb);
                    const unsigned aw[4] = {A.x, A.y, A.z, A.w};
                    const unsigned bw[4] = {B.x, B.y, B.z, B.w};
                    #pragma unroll
                    for (int k = 0; k < 4; ++k) {
                        __half2 va = __hfma2(u2h2(aw[k]), u2h2(sa), u2h2(ca));
                        __half2 vb = __hfma2(u2h2(bw[k]), u2h2(sb), u2h2(cb));
                        __half2 pr = __hmul2(va, vb);    // leaf product
                        sum1[k] = (a1 == 0) ? pr : __hadd2(sum1[k], pr);
                    }
                }
                #pragma unroll
                for (int k = 0; k < 4; ++k)
                    prod2[k] = (a2 == 0) ? sum1[k] : __hmul2(prod2[k], sum1[k]);
            }
            #pragma unroll
            for (int k = 0; k < 4; ++k) {                // top sum in f32
                float2 pf = __half22float2(prod2[k]);
                accf[2 * k]     += pf.x;
                accf[2 * k + 1] += pf.y;
            }
        }

        // lanes 4i..4i+3 cover cols w*32..w*32+31 = 128 B contiguous (full line)
        float* dst = out + (size_t)o * BATCH + w * 32 + cg * 8;
        f32x4 o0 = {accf[0], accf[1], accf[2], accf[3]};
        f32x4 o1 = {accf[4], accf[5], accf[6], accf[7]};
        __builtin_nontemporal_store(o0, reinterpret_cast<f32x4*>(dst));
        __builtin_nontemporal_store(o1, reinterpret_cast<f32x4*>(dst) + 1);
    }
}

// ---------------- fallback (round-1 kernel) if ws too small ----------------
__device__ __forceinline__ float Hval(int k, const float* __restrict__ x, int b) {
    if (k < 2) return (float)k;
    float v = x[((k - 2) >> 1) * BATCH + b];
    return (k & 1) ? 1.0f - v : v;
}

__global__ __launch_bounds__(256) void knowledge_fused_kernel(
    const float* __restrict__ x,
    const int2* __restrict__ idx0,
    const int2* __restrict__ idx1,
    const int2* __restrict__ idx2,
    const int2* __restrict__ idx3,
    float* __restrict__ out)
{
    const int i = blockIdx.x;
    const int b = blockIdx.y * blockDim.x + threadIdx.x;
    const int2 p3 = idx3[i];
    float acc3 = 0.0f;
    #pragma unroll
    for (int t = 0; t < 2; ++t) {
        const int2 p2 = idx2[t ? p3.y : p3.x];
        float prod2 = 1.0f;
        #pragma unroll
        for (int u = 0; u < 2; ++u) {
            const int2 p1 = idx1[u ? p2.y : p2.x];
            float sum1 = 0.0f;
            #pragma unroll
            for (int v = 0; v < 2; ++v) {
                const int2 p0 = idx0[v ? p1.y : p1.x];
                sum1 += Hval(p0.x, x, b) * Hval(p0.y, x, b);
            }
            prod2 *= sum1;
        }
        acc3 += prod2;
    }
    out[(size_t)i * BATCH + b] = acc3;
}

extern "C" void kernel_launch(void* const* d_in, const int* in_sizes, int n_in,
                              void* d_out, int out_size, void* d_ws, size_t ws_size,
                              hipStream_t stream) {
    const float* x    = (const float*)d_in[0];
    const int2*  idx0 = (const int2*)d_in[1];
    const int2*  idx1 = (const int2*)d_in[2];
    const int2*  idx2 = (const int2*)d_in[3];
    const int2*  idx3 = (const int2*)d_in[4];
    float* out = (float*)d_out;

    const size_t t_bytes   = (size_t)N_OUT * 8 * sizeof(unsigned);   // 128 KB
    const size_t xh2_bytes = (size_t)NW32 * W32BYTES;                // 4 MB
    if (ws_size >= t_bytes + xh2_bytes) {
        unsigned* T   = (unsigned*)d_ws;
        char*     xh2 = (char*)d_ws + t_bytes;
        prep_kernel<<<256, 256, 0, stream>>>(x, idx0, idx1, idx2, idx3, T, xh2);
        knowledge_main<<<256, 512, 0, stream>>>(xh2, (const uint4*)T, out);
    } else {
        dim3 grid(N_OUT, BATCH / 256);
        knowledge_fused_kernel<<<grid, 256, 0, stream>>>(x, idx0, idx1, idx2, idx3, out);
    }
}

// Round 13
// 18.605 us; speedup vs baseline: 2.0285x; 1.0310x over previous
//
#include <hip/hip_runtime.h>
#include <hip/hip_fp16.h>

#define BATCH  1024
#define NVARS  2048
#define N_OUT  4096

#define W32BYTES (NVARS * 64)    // 128 KB per 32-col window (fp16, row = 64 B)
#define NW32     (BATCH / 32)    // 32 windows

typedef float f32x4 __attribute__((ext_vector_type(4)));
typedef unsigned u32x4 __attribute__((ext_vector_type(4)));

__device__ __forceinline__ __half2 u2h2(unsigned u) {
    union { unsigned u; __half2 h; } c; c.u = u; return c.h;
}
__device__ __forceinline__ unsigned h22u(__half2 h) {
    union { unsigned u; __half2 h; } c; c.h = h; return c.u;
}
__device__ __forceinline__ void sel2sc(unsigned sel, unsigned& s, unsigned& c) {
    // half2 constants: 1.0h2 = 0x3C003C00, -1.0h2 = 0xBC00BC00
    c = (sel & 1u) ? 0x3C003C00u : 0u;
    s = (sel == 2u) ? 0x3C003C00u : (sel == 3u) ? 0xBC00BC00u : 0u;
}

// ---------------- prep: LDS-tile transpose to 32-col-window fp16 + T-flatten ----
// xh2: [32 w][2048 r][32 cols fp16 = 64 B]; byte(w,r) = w*131072 + r*64
// T[i*8+m] = leafA | leafB<<16, leaf = sel<<11 | row. sel:0->0,1->1,2->x,3->1-x
// All outputs stored NONTEMPORAL so no XCD's L2 holds them dirty: main's
// XCD-affine stage then pulls clean lines into its OWN L2.
__global__ __launch_bounds__(256) void prep_kernel(
    const float* __restrict__ x,
    const int2* __restrict__ idx0,
    const int2* __restrict__ idx1,
    const int2* __restrict__ idx2,
    const int2* __restrict__ idx3,
    unsigned* __restrict__ T,
    char* __restrict__ xh2)
{
    __shared__ char tile[64 * 272];    // 64 rows x 128 cols fp16, 272B padded rows

    const int bid = blockIdx.x;        // 256 blocks
    const int tid = threadIdx.x;
    const int rt  = bid >> 3;          // row tile 0..31
    const int ct  = bid & 7;           // col tile 0..7 (128 cols each)
    const int r0  = rt * 64;

    // ---- T-flatten on blocks 0..15 ----
    if (bid < 16) {
        const int i = bid * 256 + tid;
        int2 p3 = idx3[i];
        int n = 0;
        #pragma unroll
        for (int t = 0; t < 2; ++t) {
            int2 p2 = idx2[t ? p3.y : p3.x];
            #pragma unroll
            for (int u = 0; u < 2; ++u) {
                int2 p1 = idx1[u ? p2.y : p2.x];
                #pragma unroll
                for (int v = 0; v < 2; ++v) {
                    int2 p0 = idx0[v ? p1.y : p1.x];
                    unsigned w = 0;
                    #pragma unroll
                    for (int e = 0; e < 2; ++e) {
                        int k = e ? p0.y : p0.x;
                        unsigned code;
                        if (k < 2) code = (unsigned)k << 11;
                        else       code = ((2u + (k & 1)) << 11) | ((unsigned)(k - 2) >> 1);
                        w |= code << (16 * e);
                    }
                    __builtin_nontemporal_store(w, &T[(size_t)i * 8 + n]);
                    ++n;
                }
            }
        }
    }

    // ---- phase A: coalesced read of 64 rows x 128 cols, cvt fp16 into tile ----
    {
        const int r_l = tid >> 5;      // 0..7
        const int c4  = tid & 31;      // 0..31 float4 units
        #pragma unroll
        for (int q = 0; q < 8; ++q) {
            const int rr = q * 8 + r_l;                 // tile row 0..63
            float4 v = ((const float4*)x)[(size_t)(r0 + rr) * 256 + ct * 32 + c4];
            unsigned h0 = h22u(__floats2half2_rn(v.x, v.y));
            unsigned h1 = h22u(__floats2half2_rn(v.z, v.w));
            unsigned* p = (unsigned*)(tile + rr * 272 + c4 * 8);
            p[0] = h0; p[1] = h1;
        }
    }
    __syncthreads();

    // ---- phase B: write w32-major NT; per inst 64 lanes = 1 KB contiguous ----
    {
        const int wl = tid & 3;        // 16-B piece within 64-B row
        const int r2 = tid >> 2;       // 0..63
        #pragma unroll
        for (int g = 0; g < 4; ++g) {  // 32-col group within the 128-col tile
            u32x4 v = *reinterpret_cast<const u32x4*>(tile + r2 * 272 + g * 64 + wl * 16);
            const int w32 = ct * 4 + g;
            __builtin_nontemporal_store(
                v, reinterpret_cast<u32x4*>(
                       xh2 + (size_t)w32 * W32BYTES + (r0 + r2) * 64 + wl * 16));
        }
    }
}

// ---------------- main: 128 KiB LDS window, 1024 threads (16 waves/CU) --------
// 256 blocks x 1024 threads, 1 block/CU. XCD k (= bx&7) owns windows 4k..4k+3
// (all 8 chunk-blocks of a window share the XCD -> stage hits own L2 after
// first pull). Thread = (output ol, col-group cg of 8 cols); 2 passes.
// Lanes 4i..4i+3 store 128 B contiguous -> full-line NT stores.
__global__ __launch_bounds__(1024) void knowledge_main(
    const char* __restrict__ xh2,
    const uint4* __restrict__ T4,     // 2 x uint4 per output (8 packed pair-words)
    float* __restrict__ out)
{
    __shared__ char lds[131072];      // the 32-col window: row r at byte r*64

    const int bx   = blockIdx.x;      // 256
    const int tid  = threadIdx.x;     // 0..1023
    const int xcd  = bx & 7;
    const int slot = bx >> 3;         // 0..31
    const int w    = xcd * 4 + (slot & 3);   // window 0..31 (cols w*32..)
    const int chunk= slot >> 2;       // 0..7 (512 outputs each)

    // ---- stage: linear 128 KiB copy (1 KB contiguous per wave-instr) ----
    {
        const char* src = xh2 + (size_t)w * W32BYTES;
        #pragma unroll
        for (int it = 0; it < 8; ++it) {
            const int u = it * 1024 + tid;         // 16-B unit 0..8191
            *(uint4*)(lds + u * 16) = *(const uint4*)(src + u * 16);
        }
    }
    __syncthreads();

    const int cg  = tid & 3;          // col group 0..3 (8 cols)
    const int ol  = tid >> 2;         // output-in-pass 0..255
    const int cgb = cg * 16;          // byte offset within 64-B row

    int o = chunk * 512 + ol;         // pass-0 output
    uint4 t0 = T4[(size_t)o * 2];
    uint4 t1 = T4[(size_t)o * 2 + 1];

    #pragma unroll 1
    for (int pass = 0; pass < 2; ++pass) {
        const unsigned tw[8] = {t0.x, t0.y, t0.z, t0.w, t1.x, t1.y, t1.z, t1.w};

        // prefetch next pass's T while this pass computes
        if (pass == 0) {
            t0 = T4[(size_t)(o + 256) * 2];
            t1 = T4[(size_t)(o + 256) * 2 + 1];
        }

        float accf[8];
        #pragma unroll
        for (int k = 0; k < 8; ++k) accf[k] = 0.f;

        #pragma unroll
        for (int a3 = 0; a3 < 2; ++a3) {                 // top SumLayer
            __half2 prod2[4];
            #pragma unroll
            for (int a2 = 0; a2 < 2; ++a2) {             // ProductLayer
                __half2 sum1[4];
                #pragma unroll
                for (int a1 = 0; a1 < 2; ++a1) {         // SumLayer
                    const int m = a3 * 4 + a2 * 2 + a1;
                    const unsigned wv = tw[m];
                    uint4 A = *(const uint4*)(lds + ((wv & 0x7FFu) << 6) + cgb);
                    uint4 B = *(const uint4*)(lds + (((wv >> 16) & 0x7FFu) << 6) + cgb);
                    unsigned sa, ca, sb, cb;
                    sel2sc((wv >> 11) & 3u, sa, ca);
                    sel2sc((wv >> 27) & 3u, sb, cb);
                    const unsigned aw[4] = {A.x, A.y, A.z, A.w};
                    const unsigned bw[4] = {B.x, B.y, B.z, B.w};
                    #pragma unroll
                    for (int k = 0; k < 4; ++k) {
                        __half2 va = __hfma2(u2h2(aw[k]), u2h2(sa), u2h2(ca));
                        __half2 vb = __hfma2(u2h2(bw[k]), u2h2(sb), u2h2(cb));
                        __half2 pr = __hmul2(va, vb);    // leaf product
                        sum1[k] = (a1 == 0) ? pr : __hadd2(sum1[k], pr);
                    }
                }
                #pragma unroll
                for (int k = 0; k < 4; ++k)
                    prod2[k] = (a2 == 0) ? sum1[k] : __hmul2(prod2[k], sum1[k]);
            }
            #pragma unroll
            for (int k = 0; k < 4; ++k) {                // top sum in f32
                float2 pf = __half22float2(prod2[k]);
                accf[2 * k]     += pf.x;
                accf[2 * k + 1] += pf.y;
            }
        }

        // lanes 4i..4i+3 cover cols w*32..w*32+31 = 128 B contiguous (full line)
        float* dst = out + (size_t)o * BATCH + w * 32 + cg * 8;
        f32x4 o0 = {accf[0], accf[1], accf[2], accf[3]};
        f32x4 o1 = {accf[4], accf[5], accf[6], accf[7]};
        __builtin_nontemporal_store(o0, reinterpret_cast<f32x4*>(dst));
        __builtin_nontemporal_store(o1, reinterpret_cast<f32x4*>(dst) + 1);

        o += 256;
    }
}

// ---------------- fallback (round-1 kernel) if ws too small ----------------
__device__ __forceinline__ float Hval(int k, const float* __restrict__ x, int b) {
    if (k < 2) return (float)k;
    float v = x[((k - 2) >> 1) * BATCH + b];
    return (k & 1) ? 1.0f - v : v;
}

__global__ __launch_bounds__(256) void knowledge_fused_kernel(
    const float* __restrict__ x,
    const int2* __restrict__ idx0,
    const int2* __restrict__ idx1,
    const int2* __restrict__ idx2,
    const int2* __restrict__ idx3,
    float* __restrict__ out)
{
    const int i = blockIdx.x;
    const int b = blockIdx.y * blockDim.x + threadIdx.x;
    const int2 p3 = idx3[i];
    float acc3 = 0.0f;
    #pragma unroll
    for (int t = 0; t < 2; ++t) {
        const int2 p2 = idx2[t ? p3.y : p3.x];
        float prod2 = 1.0f;
        #pragma unroll
        for (int u = 0; u < 2; ++u) {
            const int2 p1 = idx1[u ? p2.y : p2.x];
            float sum1 = 0.0f;
            #pragma unroll
            for (int v = 0; v < 2; ++v) {
                const int2 p0 = idx0[v ? p1.y : p1.x];
                sum1 += Hval(p0.x, x, b) * Hval(p0.y, x, b);
            }
            prod2 *= sum1;
        }
        acc3 += prod2;
    }
    out[(size_t)i * BATCH + b] = acc3;
}

extern "C" void kernel_launch(void* const* d_in, const int* in_sizes, int n_in,
                              void* d_out, int out_size, void* d_ws, size_t ws_size,
                              hipStream_t stream) {
    const float* x    = (const float*)d_in[0];
    const int2*  idx0 = (const int2*)d_in[1];
    const int2*  idx1 = (const int2*)d_in[2];
    const int2*  idx2 = (const int2*)d_in[3];
    const int2*  idx3 = (const int2*)d_in[4];
    float* out = (float*)d_out;

    const size_t t_bytes   = (size_t)N_OUT * 8 * sizeof(unsigned);   // 128 KB
    const size_t xh2_bytes = (size_t)NW32 * W32BYTES;                // 4 MB
    if (ws_size >= t_bytes + xh2_bytes) {
        unsigned* T   = (unsigned*)d_ws;
        char*     xh2 = (char*)d_ws + t_bytes;
        prep_kernel<<<256, 256, 0, stream>>>(x, idx0, idx1, idx2, idx3, T, xh2);
        knowledge_main<<<256, 1024, 0, stream>>>(xh2, (const uint4*)T, out);
    } else {
        dim3 grid(N_OUT, BATCH / 256);
        knowledge_fused_kernel<<<grid, 256, 0, stream>>>(x, idx0, idx1, idx2, idx3, out);
    }
}